// Round 2
// baseline (360.549 us; speedup 1.0000x reference)
//
#include <hip/hip_runtime.h>
#include <hip/hip_bf16.h>

#define GAMMA 0.002f
#define NROWS 8192
#define MROWS 8192
#define DDIM  512

typedef __attribute__((ext_vector_type(8))) short bf16x8;
typedef __attribute__((ext_vector_type(4))) float f32x4;
typedef __attribute__((ext_vector_type(8))) unsigned short ushort8;

static __device__ __forceinline__ unsigned short f32_to_bf16_rne(float f) {
    unsigned int u = __float_as_uint(f);
    unsigned int lsb = (u >> 16) & 1u;
    u += 0x7fffu + lsb;
    return (unsigned short)(u >> 16);
}

// One wave (64 threads) per row: cast fp32 row -> bf16, compute fp32 row norm.
__global__ __launch_bounds__(64) void prep_kernel(const float* __restrict__ src,
                                                  unsigned short* __restrict__ dstb,
                                                  float* __restrict__ sq) {
    const int row  = blockIdx.x;
    const int lane = threadIdx.x;

    const float4* p = (const float4*)(src + (size_t)row * DDIM) + lane * 2;
    float4 f0 = p[0];
    float4 f1 = p[1];

    float s = f0.x*f0.x + f0.y*f0.y + f0.z*f0.z + f0.w*f0.w
            + f1.x*f1.x + f1.y*f1.y + f1.z*f1.z + f1.w*f1.w;

    float t[8] = {f0.x, f0.y, f0.z, f0.w, f1.x, f1.y, f1.z, f1.w};
    ushort8 hv;
#pragma unroll
    for (int i = 0; i < 8; ++i) hv[i] = f32_to_bf16_rne(t[i]);
    *(ushort8*)(dstb + (size_t)row * DDIM + lane * 8) = hv;

#pragma unroll
    for (int off = 32; off > 0; off >>= 1) s += __shfl_down(s, off);
    if (lane == 0) sq[row] = s;
}

// 128x128 output tile per block, 256 threads (4 waves, 2x2), BK=64.
// A = x (bf16, N x D row-major), B = y (bf16, M x D row-major), C = A*B^T,
// fused RBF epilogue with LDS-transposed coalesced float4 stores.
//
// LDS layout: rows of 128 B, split into 8 chunks of 16 B, chunk position
// XOR-swizzled by (row & 7). Swizzle applied at staging via the *global*
// source address (permutation stays inside one 128-B line -> coalescing
// preserved; global_load_lds dst is wave-uniform base + lane*16).
__global__ __launch_bounds__(256) void rbf_gemm_kernel(
        const unsigned short* __restrict__ xb,
        const unsigned short* __restrict__ yb,
        const float* __restrict__ xsq,
        const float* __restrict__ ysq,
        float* __restrict__ out) {
    __shared__ __align__(16) unsigned short smem[2 * 128 * 64];  // 32 KiB
    unsigned short* smemA = smem;             // 128 rows x 128 B
    unsigned short* smemB = smem + 128 * 64;

    const int tid  = threadIdx.x;
    const int wave = tid >> 6;
    const int lane = tid & 63;

    const int rowBase = blockIdx.x * 128;
    const int colBase = blockIdx.y * 128;

    const int wm = wave >> 1;  // row half
    const int wn = wave & 1;   // col half

    f32x4 acc[4][4];
#pragma unroll
    for (int i = 0; i < 4; ++i)
#pragma unroll
        for (int j = 0; j < 4; ++j) acc[i][j] = (f32x4){0.f, 0.f, 0.f, 0.f};

    // Staging: each wave-instr stages 8 rows x 128 B = 1 KiB.
    // LDS chunk position p = lane&7 of row (seg*8 + lane>>3) must hold
    // global chunk p ^ (row&7).
    const int srow   = lane >> 3;                 // row within 8-row segment
    const int schunk = (lane & 7) ^ srow;         // global 16-B chunk to fetch

    // Fragment mapping (16x16x32 MFMA, A and B identical for B^T layout):
    const int fr = lane & 15;   // row within 16-row tile
    const int q  = lane >> 4;   // k-quad 0..3

    for (int kt = 0; kt < DDIM / 64; ++kt) {
#pragma unroll
        for (int r = 0; r < 4; ++r) {
            const int seg = r * 4 + wave;  // 0..15, 8 rows each
            {
                const char* g = (const char*)xb
                    + (size_t)(rowBase + seg * 8 + srow) * (DDIM * 2)
                    + kt * 128 + schunk * 16;
                __builtin_amdgcn_global_load_lds(
                    (__attribute__((address_space(1))) void*)g,
                    (__attribute__((address_space(3))) void*)((char*)smemA + seg * 1024),
                    16, 0, 0);
            }
            {
                const char* g = (const char*)yb
                    + (size_t)(colBase + seg * 8 + srow) * (DDIM * 2)
                    + kt * 128 + schunk * 16;
                __builtin_amdgcn_global_load_lds(
                    (__attribute__((address_space(1))) void*)g,
                    (__attribute__((address_space(3))) void*)((char*)smemB + seg * 1024),
                    16, 0, 0);
            }
        }
        __syncthreads();

#pragma unroll
        for (int k2 = 0; k2 < 2; ++k2) {
            bf16x8 a[4], b[4];
#pragma unroll
            for (int i = 0; i < 4; ++i) {
                const int row = wm * 64 + i * 16 + fr;
                const int ch  = (k2 * 4 + q) ^ (fr & 7);   // unswizzle
                a[i] = *(const bf16x8*)((const char*)smemA + row * 128 + ch * 16);
            }
#pragma unroll
            for (int j = 0; j < 4; ++j) {
                const int row = wn * 64 + j * 16 + fr;
                const int ch  = (k2 * 4 + q) ^ (fr & 7);
                b[j] = *(const bf16x8*)((const char*)smemB + row * 128 + ch * 16);
            }
#pragma unroll
            for (int i = 0; i < 4; ++i)
#pragma unroll
                for (int j = 0; j < 4; ++j)
                    acc[i][j] = __builtin_amdgcn_mfma_f32_16x16x32_bf16(a[i], b[j], acc[i][j], 0, 0, 0);
        }
        __syncthreads();
    }

    // ---- Epilogue: exp(-gamma*max(xsq+ysq-2*dot,0)), coalesced via LDS ----
    // C/D layout: col = lane&15, row = q*4 + reg  [m89/m91].
    // Each wave transposes one 16x64 slice at a time through a private
    // 16x68-float LDS region (stride 68 -> <=2-way bank conflicts = free).
    float* wbuf = (float*)smem + wave * (16 * 68);  // 4 waves * 4352 B = 17 KiB

    float yc[4];
#pragma unroll
    for (int j = 0; j < 4; ++j) yc[j] = ysq[colBase + wn * 64 + j * 16 + fr];
    const int q4 = q * 4;

#pragma unroll
    for (int i = 0; i < 4; ++i) {
        float xr[4];
#pragma unroll
        for (int r2 = 0; r2 < 4; ++r2)
            xr[r2] = xsq[rowBase + wm * 64 + i * 16 + q4 + r2];

        __syncthreads();  // previous pass's reads done before overwrite
#pragma unroll
        for (int j = 0; j < 4; ++j) {
#pragma unroll
            for (int r2 = 0; r2 < 4; ++r2) {
                float d = xr[r2] + yc[j] - 2.0f * acc[i][j][r2];
                d = fmaxf(d, 0.0f);
                wbuf[(q4 + r2) * 68 + j * 16 + fr] = __expf(-GAMMA * d);
            }
        }
        __syncthreads();  // cross-lane LDS visibility within the wave

#pragma unroll
        for (int p = 0; p < 4; ++p) {
            const int lrow = p * 4 + q;  // 0..15
            float4 v = *(const float4*)&wbuf[lrow * 68 + fr * 4];
            const int grow = rowBase + wm * 64 + i * 16 + lrow;
            const int gcol = colBase + wn * 64 + fr * 4;
            *(float4*)(out + (size_t)grow * MROWS + gcol) = v;
        }
    }
}

extern "C" void kernel_launch(void* const* d_in, const int* in_sizes, int n_in,
                              void* d_out, int out_size, void* d_ws, size_t ws_size,
                              hipStream_t stream) {
    const float* x = (const float*)d_in[0];
    const float* y = (const float*)d_in[1];
    float* out = (float*)d_out;

    // Workspace: xb (8 MiB) | yb (8 MiB) | xsq (32 KiB) | ysq (32 KiB)
    unsigned short* xb = (unsigned short*)d_ws;
    unsigned short* yb = xb + (size_t)NROWS * DDIM;
    float* xsq = (float*)(yb + (size_t)MROWS * DDIM);
    float* ysq = xsq + NROWS;

    prep_kernel<<<NROWS, 64, 0, stream>>>(x, xb, xsq);
    prep_kernel<<<MROWS, 64, 0, stream>>>(y, yb, ysq);

    dim3 grid(NROWS / 128, MROWS / 128);
    rbf_gemm_kernel<<<grid, 256, 0, stream>>>(xb, yb, xsq, ysq, out);
}